// Round 7
// baseline (101.336 us; speedup 1.0000x reference)
//
#include <hip/hip_runtime.h>
#include <math.h>

#define B_      16
#define C_IN_   128
#define C_OUT_  3
#define W_DIM_  512
#define HW_     65536          // 256*256
#define CONV_CLAMP_ 256.0f

typedef float f32x4 __attribute__((ext_vector_type(4)));

// ---------------------------------------------------------------------------
// k_prep1: single-launch prologue, fully parallel (R6 winner, unchanged).
// One 16-lane group per (b,i): computes the three dots
//   m_k = dot(w[b], affine_w[k*128+i]) / sqrt(512) + affine_b[k*128+i]
// then style = (m1*m2+m3)/sqrt(128) and eff[b][i] directly.
// ---------------------------------------------------------------------------
__global__ __launch_bounds__(256) void k_prep1(
        const float* __restrict__ w,
        const float* __restrict__ affine_w,
        const float* __restrict__ affine_b,
        const float* __restrict__ weight,
        float* __restrict__ eff) {
    int gid   = blockIdx.x * blockDim.x + threadIdx.x;
    int group = gid >> 4;            // (b,i) pair, 0..2047
    int lane  = gid & 15;
    int b = group >> 7;              // group / 128
    int i = group & 127;

    const f32x4* wr4 = reinterpret_cast<const f32x4*>(w + (size_t)b * W_DIM_);

    float p0 = 0.f, p1 = 0.f, p2 = 0.f;
    const f32x4* a0r = reinterpret_cast<const f32x4*>(affine_w + (size_t)(i)       * W_DIM_);
    const f32x4* a1r = reinterpret_cast<const f32x4*>(affine_w + (size_t)(i + 128) * W_DIM_);
    const f32x4* a2r = reinterpret_cast<const f32x4*>(affine_w + (size_t)(i + 256) * W_DIM_);
    #pragma unroll
    for (int t = 0; t < 8; ++t) {
        f32x4 wv  = wr4[lane + t * 16];
        f32x4 av0 = a0r[lane + t * 16];
        f32x4 av1 = a1r[lane + t * 16];
        f32x4 av2 = a2r[lane + t * 16];
        p0 = fmaf(av0.x, wv.x, p0); p0 = fmaf(av0.y, wv.y, p0);
        p0 = fmaf(av0.z, wv.z, p0); p0 = fmaf(av0.w, wv.w, p0);
        p1 = fmaf(av1.x, wv.x, p1); p1 = fmaf(av1.y, wv.y, p1);
        p1 = fmaf(av1.z, wv.z, p1); p1 = fmaf(av1.w, wv.w, p1);
        p2 = fmaf(av2.x, wv.x, p2); p2 = fmaf(av2.y, wv.y, p2);
        p2 = fmaf(av2.z, wv.z, p2); p2 = fmaf(av2.w, wv.w, p2);
    }
    #pragma unroll
    for (int off = 8; off; off >>= 1) {
        p0 += __shfl_xor(p0, off, 16);
        p1 += __shfl_xor(p1, off, 16);
        p2 += __shfl_xor(p2, off, 16);
    }
    if (lane == 0) {
        const float g = 0.04419417382415922f;     // 1/sqrt(512)
        float m1 = fmaf(p0, g, affine_b[i]);
        float m2 = fmaf(p1, g, affine_b[i + 128]);
        float m3 = fmaf(p2, g, affine_b[i + 256]);
        float style = fmaf(m1, m2, m3) * 0.08838834764831845f;  // 1/sqrt(128)
        f32x4 e;
        e.x = style * weight[0 * C_IN_ + i];
        e.y = style * weight[1 * C_IN_ + i];
        e.z = style * weight[2 * C_IN_ + i];
        e.w = 0.f;
        reinterpret_cast<f32x4*>(eff)[group] = e;
    }
}

// ---------------------------------------------------------------------------
// k_main — R6 winner with ONE change: unroll 8 -> 16 (deeper load pipeline).
// 1024 blocks (64/batch), 256 thr, 4 px/thread, NT loads/stores.
// ---------------------------------------------------------------------------
__global__ __launch_bounds__(256) void k_main(
        const float* __restrict__ x,
        const float* __restrict__ eff,
        const float* __restrict__ bias,
        float* __restrict__ out) {
    __shared__ f32x4 eff_lds[C_IN_];
    int b   = blockIdx.x >> 6;       // 64 blocks per batch
    int blk = blockIdx.x & 63;

    if (threadIdx.x < C_IN_)
        eff_lds[threadIdx.x] =
            reinterpret_cast<const f32x4*>(eff)[b * C_IN_ + threadIdx.x];
    __syncthreads();

    int pix = blk * 1024 + threadIdx.x * 4;     // 256 thr * 4 px = 1024 px
    const float* xb = x + (size_t)b * C_IN_ * HW_ + pix;

    f32x4 a0 = {0.f,0.f,0.f,0.f};
    f32x4 a1 = {0.f,0.f,0.f,0.f};
    f32x4 a2 = {0.f,0.f,0.f,0.f};

    #pragma unroll 16
    for (int i = 0; i < C_IN_; ++i) {
        f32x4 xv = __builtin_nontemporal_load(
            reinterpret_cast<const f32x4*>(xb + ((size_t)i << 16)));
        f32x4 e  = eff_lds[i];
        a0.x = fmaf(xv.x, e.x, a0.x);
        a0.y = fmaf(xv.y, e.x, a0.y);
        a0.z = fmaf(xv.z, e.x, a0.z);
        a0.w = fmaf(xv.w, e.x, a0.w);
        a1.x = fmaf(xv.x, e.y, a1.x);
        a1.y = fmaf(xv.y, e.y, a1.y);
        a1.z = fmaf(xv.z, e.y, a1.z);
        a1.w = fmaf(xv.w, e.y, a1.w);
        a2.x = fmaf(xv.x, e.z, a2.x);
        a2.y = fmaf(xv.y, e.z, a2.y);
        a2.z = fmaf(xv.z, e.z, a2.z);
        a2.w = fmaf(xv.w, e.z, a2.w);
    }

    float b0 = bias[0], b1 = bias[1], b2 = bias[2];
    auto clip4 = [](f32x4 v, float bb) {
        f32x4 r;
        r.x = fminf(fmaxf(v.x + bb, -CONV_CLAMP_), CONV_CLAMP_);
        r.y = fminf(fmaxf(v.y + bb, -CONV_CLAMP_), CONV_CLAMP_);
        r.z = fminf(fmaxf(v.z + bb, -CONV_CLAMP_), CONV_CLAMP_);
        r.w = fminf(fmaxf(v.w + bb, -CONV_CLAMP_), CONV_CLAMP_);
        return r;
    };

    float* ob = out + (size_t)b * C_OUT_ * HW_ + pix;
    __builtin_nontemporal_store(clip4(a0, b0), reinterpret_cast<f32x4*>(ob));
    __builtin_nontemporal_store(clip4(a1, b1), reinterpret_cast<f32x4*>(ob + HW_));
    __builtin_nontemporal_store(clip4(a2, b2), reinterpret_cast<f32x4*>(ob + 2 * HW_));
}

// ---------------------------------------------------------------------------
extern "C" void kernel_launch(void* const* d_in, const int* in_sizes, int n_in,
                              void* d_out, int out_size, void* d_ws, size_t ws_size,
                              hipStream_t stream) {
    const float* x        = (const float*)d_in[0];
    const float* w        = (const float*)d_in[1];
    const float* weight   = (const float*)d_in[2];
    const float* bias     = (const float*)d_in[3];
    const float* affine_w = (const float*)d_in[4];
    const float* affine_b = (const float*)d_in[5];
    float* out = (float*)d_out;

    float* eff = (float*)d_ws;                      // 16*128 f32x4

    k_prep1<<<128,  256, 0, stream>>>(w, affine_w, affine_b, weight, eff);
    k_main <<<1024, 256, 0, stream>>>(x, eff, bias, out);
}

// Round 8
// 90.324 us; speedup vs baseline: 1.1219x; 1.1219x over previous
//
#include <hip/hip_runtime.h>
#include <math.h>

#define B_      16
#define C_IN_   128
#define C_OUT_  3
#define W_DIM_  512
#define HW_     65536          // 256*256
#define CONV_CLAMP_ 256.0f

typedef float f32x4 __attribute__((ext_vector_type(4)));

// ---------------------------------------------------------------------------
// k_prep1: single-launch prologue, fully parallel (R6 winner, unchanged).
// ---------------------------------------------------------------------------
__global__ __launch_bounds__(256) void k_prep1(
        const float* __restrict__ w,
        const float* __restrict__ affine_w,
        const float* __restrict__ affine_b,
        const float* __restrict__ weight,
        float* __restrict__ eff) {
    int gid   = blockIdx.x * blockDim.x + threadIdx.x;
    int group = gid >> 4;            // (b,i) pair, 0..2047
    int lane  = gid & 15;
    int b = group >> 7;              // group / 128
    int i = group & 127;

    const f32x4* wr4 = reinterpret_cast<const f32x4*>(w + (size_t)b * W_DIM_);

    float p0 = 0.f, p1 = 0.f, p2 = 0.f;
    const f32x4* a0r = reinterpret_cast<const f32x4*>(affine_w + (size_t)(i)       * W_DIM_);
    const f32x4* a1r = reinterpret_cast<const f32x4*>(affine_w + (size_t)(i + 128) * W_DIM_);
    const f32x4* a2r = reinterpret_cast<const f32x4*>(affine_w + (size_t)(i + 256) * W_DIM_);
    #pragma unroll
    for (int t = 0; t < 8; ++t) {
        f32x4 wv  = wr4[lane + t * 16];
        f32x4 av0 = a0r[lane + t * 16];
        f32x4 av1 = a1r[lane + t * 16];
        f32x4 av2 = a2r[lane + t * 16];
        p0 = fmaf(av0.x, wv.x, p0); p0 = fmaf(av0.y, wv.y, p0);
        p0 = fmaf(av0.z, wv.z, p0); p0 = fmaf(av0.w, wv.w, p0);
        p1 = fmaf(av1.x, wv.x, p1); p1 = fmaf(av1.y, wv.y, p1);
        p1 = fmaf(av1.z, wv.z, p1); p1 = fmaf(av1.w, wv.w, p1);
        p2 = fmaf(av2.x, wv.x, p2); p2 = fmaf(av2.y, wv.y, p2);
        p2 = fmaf(av2.z, wv.z, p2); p2 = fmaf(av2.w, wv.w, p2);
    }
    #pragma unroll
    for (int off = 8; off; off >>= 1) {
        p0 += __shfl_xor(p0, off, 16);
        p1 += __shfl_xor(p1, off, 16);
        p2 += __shfl_xor(p2, off, 16);
    }
    if (lane == 0) {
        const float g = 0.04419417382415922f;     // 1/sqrt(512)
        float m1 = fmaf(p0, g, affine_b[i]);
        float m2 = fmaf(p1, g, affine_b[i + 128]);
        float m3 = fmaf(p2, g, affine_b[i + 256]);
        float style = fmaf(m1, m2, m3) * 0.08838834764831845f;  // 1/sqrt(128)
        f32x4 e;
        e.x = style * weight[0 * C_IN_ + i];
        e.y = style * weight[1 * C_IN_ + i];
        e.z = style * weight[2 * C_IN_ + i];
        e.w = 0.f;
        reinterpret_cast<f32x4*>(eff)[group] = e;
    }
}

// ---------------------------------------------------------------------------
// k_main — single lever vs the R6 winner: 512 blocks (32/batch), 8 px/thread
// as two NT float4 segments -> 8 KB contiguous per channel per block.
// No rotation. unroll 8 (R6 setting).
// ---------------------------------------------------------------------------
__global__ __launch_bounds__(256) void k_main(
        const float* __restrict__ x,
        const float* __restrict__ eff,
        const float* __restrict__ bias,
        float* __restrict__ out) {
    __shared__ f32x4 eff_lds[C_IN_];
    int b   = blockIdx.x >> 5;       // 32 blocks per batch
    int blk = blockIdx.x & 31;

    if (threadIdx.x < C_IN_)
        eff_lds[threadIdx.x] =
            reinterpret_cast<const f32x4*>(eff)[b * C_IN_ + threadIdx.x];
    __syncthreads();

    const int pix = blk * 2048 + threadIdx.x * 4;   // segment 0; segment 1 at +1024
    const float* xb = x + (size_t)b * C_IN_ * HW_ + pix;

    f32x4 aA0 = {0.f,0.f,0.f,0.f}, aA1 = {0.f,0.f,0.f,0.f}, aA2 = {0.f,0.f,0.f,0.f};
    f32x4 aB0 = {0.f,0.f,0.f,0.f}, aB1 = {0.f,0.f,0.f,0.f}, aB2 = {0.f,0.f,0.f,0.f};

    #pragma unroll 8
    for (int i = 0; i < C_IN_; ++i) {
        const float* p = xb + ((size_t)i << 16);
        f32x4 x0 = __builtin_nontemporal_load(reinterpret_cast<const f32x4*>(p));
        f32x4 x1 = __builtin_nontemporal_load(reinterpret_cast<const f32x4*>(p + 1024));
        f32x4 e  = eff_lds[i];
        aA0.x = fmaf(x0.x, e.x, aA0.x); aA0.y = fmaf(x0.y, e.x, aA0.y);
        aA0.z = fmaf(x0.z, e.x, aA0.z); aA0.w = fmaf(x0.w, e.x, aA0.w);
        aA1.x = fmaf(x0.x, e.y, aA1.x); aA1.y = fmaf(x0.y, e.y, aA1.y);
        aA1.z = fmaf(x0.z, e.y, aA1.z); aA1.w = fmaf(x0.w, e.y, aA1.w);
        aA2.x = fmaf(x0.x, e.z, aA2.x); aA2.y = fmaf(x0.y, e.z, aA2.y);
        aA2.z = fmaf(x0.z, e.z, aA2.z); aA2.w = fmaf(x0.w, e.z, aA2.w);
        aB0.x = fmaf(x1.x, e.x, aB0.x); aB0.y = fmaf(x1.y, e.x, aB0.y);
        aB0.z = fmaf(x1.z, e.x, aB0.z); aB0.w = fmaf(x1.w, e.x, aB0.w);
        aB1.x = fmaf(x1.x, e.y, aB1.x); aB1.y = fmaf(x1.y, e.y, aB1.y);
        aB1.z = fmaf(x1.z, e.y, aB1.z); aB1.w = fmaf(x1.w, e.y, aB1.w);
        aB2.x = fmaf(x1.x, e.z, aB2.x); aB2.y = fmaf(x1.y, e.z, aB2.y);
        aB2.z = fmaf(x1.z, e.z, aB2.z); aB2.w = fmaf(x1.w, e.z, aB2.w);
    }

    float b0 = bias[0], b1 = bias[1], b2 = bias[2];
    auto clip4 = [](f32x4 v, float bb) {
        f32x4 r;
        r.x = fminf(fmaxf(v.x + bb, -CONV_CLAMP_), CONV_CLAMP_);
        r.y = fminf(fmaxf(v.y + bb, -CONV_CLAMP_), CONV_CLAMP_);
        r.z = fminf(fmaxf(v.z + bb, -CONV_CLAMP_), CONV_CLAMP_);
        r.w = fminf(fmaxf(v.w + bb, -CONV_CLAMP_), CONV_CLAMP_);
        return r;
    };

    float* ob = out + (size_t)b * C_OUT_ * HW_ + pix;
    __builtin_nontemporal_store(clip4(aA0, b0), reinterpret_cast<f32x4*>(ob));
    __builtin_nontemporal_store(clip4(aA1, b1), reinterpret_cast<f32x4*>(ob + HW_));
    __builtin_nontemporal_store(clip4(aA2, b2), reinterpret_cast<f32x4*>(ob + 2 * HW_));
    __builtin_nontemporal_store(clip4(aB0, b0), reinterpret_cast<f32x4*>(ob + 1024));
    __builtin_nontemporal_store(clip4(aB1, b1), reinterpret_cast<f32x4*>(ob + HW_ + 1024));
    __builtin_nontemporal_store(clip4(aB2, b2), reinterpret_cast<f32x4*>(ob + 2 * HW_ + 1024));
}

// ---------------------------------------------------------------------------
extern "C" void kernel_launch(void* const* d_in, const int* in_sizes, int n_in,
                              void* d_out, int out_size, void* d_ws, size_t ws_size,
                              hipStream_t stream) {
    const float* x        = (const float*)d_in[0];
    const float* w        = (const float*)d_in[1];
    const float* weight   = (const float*)d_in[2];
    const float* bias     = (const float*)d_in[3];
    const float* affine_w = (const float*)d_in[4];
    const float* affine_b = (const float*)d_in[5];
    float* out = (float*)d_out;

    float* eff = (float*)d_ws;                      // 16*128 f32x4

    k_prep1<<<128, 256, 0, stream>>>(w, affine_w, affine_b, weight, eff);
    k_main <<<512, 256, 0, stream>>>(x, eff, bias, out);
}

// Round 9
// 88.790 us; speedup vs baseline: 1.1413x; 1.0173x over previous
//
#include <hip/hip_runtime.h>
#include <math.h>

#define B_      16
#define C_IN_   128
#define C_OUT_  3
#define W_DIM_  512
#define HW_     65536          // 256*256
#define CONV_CLAMP_ 256.0f

typedef float f32x4 __attribute__((ext_vector_type(4)));

// ---------------------------------------------------------------------------
// k_prep1: single-launch prologue, fully parallel (R6 winner, unchanged).
// ---------------------------------------------------------------------------
__global__ __launch_bounds__(256) void k_prep1(
        const float* __restrict__ w,
        const float* __restrict__ affine_w,
        const float* __restrict__ affine_b,
        const float* __restrict__ weight,
        float* __restrict__ eff) {
    int gid   = blockIdx.x * blockDim.x + threadIdx.x;
    int group = gid >> 4;            // (b,i) pair, 0..2047
    int lane  = gid & 15;
    int b = group >> 7;              // group / 128
    int i = group & 127;

    const f32x4* wr4 = reinterpret_cast<const f32x4*>(w + (size_t)b * W_DIM_);

    float p0 = 0.f, p1 = 0.f, p2 = 0.f;
    const f32x4* a0r = reinterpret_cast<const f32x4*>(affine_w + (size_t)(i)       * W_DIM_);
    const f32x4* a1r = reinterpret_cast<const f32x4*>(affine_w + (size_t)(i + 128) * W_DIM_);
    const f32x4* a2r = reinterpret_cast<const f32x4*>(affine_w + (size_t)(i + 256) * W_DIM_);
    #pragma unroll
    for (int t = 0; t < 8; ++t) {
        f32x4 wv  = wr4[lane + t * 16];
        f32x4 av0 = a0r[lane + t * 16];
        f32x4 av1 = a1r[lane + t * 16];
        f32x4 av2 = a2r[lane + t * 16];
        p0 = fmaf(av0.x, wv.x, p0); p0 = fmaf(av0.y, wv.y, p0);
        p0 = fmaf(av0.z, wv.z, p0); p0 = fmaf(av0.w, wv.w, p0);
        p1 = fmaf(av1.x, wv.x, p1); p1 = fmaf(av1.y, wv.y, p1);
        p1 = fmaf(av1.z, wv.z, p1); p1 = fmaf(av1.w, wv.w, p1);
        p2 = fmaf(av2.x, wv.x, p2); p2 = fmaf(av2.y, wv.y, p2);
        p2 = fmaf(av2.z, wv.z, p2); p2 = fmaf(av2.w, wv.w, p2);
    }
    #pragma unroll
    for (int off = 8; off; off >>= 1) {
        p0 += __shfl_xor(p0, off, 16);
        p1 += __shfl_xor(p1, off, 16);
        p2 += __shfl_xor(p2, off, 16);
    }
    if (lane == 0) {
        const float g = 0.04419417382415922f;     // 1/sqrt(512)
        float m1 = fmaf(p0, g, affine_b[i]);
        float m2 = fmaf(p1, g, affine_b[i + 128]);
        float m3 = fmaf(p2, g, affine_b[i + 256]);
        float style = fmaf(m1, m2, m3) * 0.08838834764831845f;  // 1/sqrt(128)
        f32x4 e;
        e.x = style * weight[0 * C_IN_ + i];
        e.y = style * weight[1 * C_IN_ + i];
        e.z = style * weight[2 * C_IN_ + i];
        e.w = 0.f;
        reinterpret_cast<f32x4*>(eff)[group] = e;
    }
}

// ---------------------------------------------------------------------------
// k_main — single lever vs R8 winner: 256 blocks x 512 threads (16/batch),
// block owns 4096 contiguous px -> 16 KB per channel per block; waves/CU
// unchanged (8). Thread owns 8 px as two NT float4 segments at +0/+2048.
// ---------------------------------------------------------------------------
__global__ __launch_bounds__(512) void k_main(
        const float* __restrict__ x,
        const float* __restrict__ eff,
        const float* __restrict__ bias,
        float* __restrict__ out) {
    __shared__ f32x4 eff_lds[C_IN_];
    int b   = blockIdx.x >> 4;       // 16 blocks per batch
    int blk = blockIdx.x & 15;

    if (threadIdx.x < C_IN_)
        eff_lds[threadIdx.x] =
            reinterpret_cast<const f32x4*>(eff)[b * C_IN_ + threadIdx.x];
    __syncthreads();

    const int pix = blk * 4096 + threadIdx.x * 4;   // seg0; seg1 at +2048
    const float* xb = x + (size_t)b * C_IN_ * HW_ + pix;

    f32x4 aA0 = {0.f,0.f,0.f,0.f}, aA1 = {0.f,0.f,0.f,0.f}, aA2 = {0.f,0.f,0.f,0.f};
    f32x4 aB0 = {0.f,0.f,0.f,0.f}, aB1 = {0.f,0.f,0.f,0.f}, aB2 = {0.f,0.f,0.f,0.f};

    #pragma unroll 8
    for (int i = 0; i < C_IN_; ++i) {
        const float* p = xb + ((size_t)i << 16);
        f32x4 x0 = __builtin_nontemporal_load(reinterpret_cast<const f32x4*>(p));
        f32x4 x1 = __builtin_nontemporal_load(reinterpret_cast<const f32x4*>(p + 2048));
        f32x4 e  = eff_lds[i];
        aA0.x = fmaf(x0.x, e.x, aA0.x); aA0.y = fmaf(x0.y, e.x, aA0.y);
        aA0.z = fmaf(x0.z, e.x, aA0.z); aA0.w = fmaf(x0.w, e.x, aA0.w);
        aA1.x = fmaf(x0.x, e.y, aA1.x); aA1.y = fmaf(x0.y, e.y, aA1.y);
        aA1.z = fmaf(x0.z, e.y, aA1.z); aA1.w = fmaf(x0.w, e.y, aA1.w);
        aA2.x = fmaf(x0.x, e.z, aA2.x); aA2.y = fmaf(x0.y, e.z, aA2.y);
        aA2.z = fmaf(x0.z, e.z, aA2.z); aA2.w = fmaf(x0.w, e.z, aA2.w);
        aB0.x = fmaf(x1.x, e.x, aB0.x); aB0.y = fmaf(x1.y, e.x, aB0.y);
        aB0.z = fmaf(x1.z, e.x, aB0.z); aB0.w = fmaf(x1.w, e.x, aB0.w);
        aB1.x = fmaf(x1.x, e.y, aB1.x); aB1.y = fmaf(x1.y, e.y, aB1.y);
        aB1.z = fmaf(x1.z, e.y, aB1.z); aB1.w = fmaf(x1.w, e.y, aB1.w);
        aB2.x = fmaf(x1.x, e.z, aB2.x); aB2.y = fmaf(x1.y, e.z, aB2.y);
        aB2.z = fmaf(x1.z, e.z, aB2.z); aB2.w = fmaf(x1.w, e.z, aB2.w);
    }

    float b0 = bias[0], b1 = bias[1], b2 = bias[2];
    auto clip4 = [](f32x4 v, float bb) {
        f32x4 r;
        r.x = fminf(fmaxf(v.x + bb, -CONV_CLAMP_), CONV_CLAMP_);
        r.y = fminf(fmaxf(v.y + bb, -CONV_CLAMP_), CONV_CLAMP_);
        r.z = fminf(fmaxf(v.z + bb, -CONV_CLAMP_), CONV_CLAMP_);
        r.w = fminf(fmaxf(v.w + bb, -CONV_CLAMP_), CONV_CLAMP_);
        return r;
    };

    float* ob = out + (size_t)b * C_OUT_ * HW_ + pix;
    __builtin_nontemporal_store(clip4(aA0, b0), reinterpret_cast<f32x4*>(ob));
    __builtin_nontemporal_store(clip4(aA1, b1), reinterpret_cast<f32x4*>(ob + HW_));
    __builtin_nontemporal_store(clip4(aA2, b2), reinterpret_cast<f32x4*>(ob + 2 * HW_));
    __builtin_nontemporal_store(clip4(aB0, b0), reinterpret_cast<f32x4*>(ob + 2048));
    __builtin_nontemporal_store(clip4(aB1, b1), reinterpret_cast<f32x4*>(ob + HW_ + 2048));
    __builtin_nontemporal_store(clip4(aB2, b2), reinterpret_cast<f32x4*>(ob + 2 * HW_ + 2048));
}

// ---------------------------------------------------------------------------
extern "C" void kernel_launch(void* const* d_in, const int* in_sizes, int n_in,
                              void* d_out, int out_size, void* d_ws, size_t ws_size,
                              hipStream_t stream) {
    const float* x        = (const float*)d_in[0];
    const float* w        = (const float*)d_in[1];
    const float* weight   = (const float*)d_in[2];
    const float* bias     = (const float*)d_in[3];
    const float* affine_w = (const float*)d_in[4];
    const float* affine_b = (const float*)d_in[5];
    float* out = (float*)d_out;

    float* eff = (float*)d_ws;                      // 16*128 f32x4

    k_prep1<<<128, 256, 0, stream>>>(w, affine_w, affine_b, weight, eff);
    k_main <<<256, 512, 0, stream>>>(x, eff, bias, out);
}